// Round 1
// 878.402 us; speedup vs baseline: 1.1254x; 1.1254x over previous
//
#include <hip/hip_runtime.h>
#include <hip/hip_bf16.h>

#define IN_F   4096
#define OUT_F  11008
#define MROWS  4096   // 2*2048 rows of x
#define BM     256
#define BN     256
#define BK     64
#define NT     (IN_F / BK)                           // 64 K-tiles
#define CVT_BLOCKS ((MROWS * IN_F) / (256 * 8))      // 8192
#define DEQ_BLOCKS ((OUT_F * IN_F) / (256 * 8))      // 22016

typedef __bf16 bf16x8 __attribute__((ext_vector_type(8)));
typedef float  f32x4  __attribute__((ext_vector_type(4)));

// ---------------------------------------------------------------------------
// Fused prep (UNCHANGED this round — isolating the gemm rewrite; prep will
// surface in top-5 counters next round for diagnosis).
// ---------------------------------------------------------------------------
__global__ __launch_bounds__(256) void k_prep(const float* __restrict__ x,
                                              const int* __restrict__ q,
                                              const int* __restrict__ mask,
                                              const float* __restrict__ scales,
                                              __hip_bfloat16* __restrict__ xb,
                                              __hip_bfloat16* __restrict__ Wb)
{
    if (blockIdx.x < CVT_BLOCKS) {
        const long long t    = (long long)blockIdx.x * 256 + threadIdx.x;
        const long long base = t * 8;
        const float4 a = *(const float4*)(x + base);
        const float4 b = *(const float4*)(x + base + 4);
        float f[8] = {a.x, a.y, a.z, a.w, b.x, b.y, b.z, b.w};
        union { int4 v; __hip_bfloat16 h[8]; } u;
#pragma unroll
        for (int j = 0; j < 8; ++j) u.h[j] = __float2bfloat16(f[j]);
        *(int4*)(xb + base) = u.v;
    } else {
        const long long t    = (long long)(blockIdx.x - CVT_BLOCKS) * 256 + threadIdx.x;
        const long long base = t * 8;
        const int   g = (int)(base >> 6);
        const float s = scales[g];
        const int4 q0 = *(const int4*)(q + base);
        const int4 q1 = *(const int4*)(q + base + 4);
        const int4 m0 = *(const int4*)(mask + base);
        const int4 m1 = *(const int4*)(mask + base + 4);
        const float c = 2.0f / 7.0f;
        int qa[8] = {q0.x, q0.y, q0.z, q0.w, q1.x, q1.y, q1.z, q1.w};
        int ma[8] = {m0.x, m0.y, m0.z, m0.w, m1.x, m1.y, m1.z, m1.w};
        union { int4 v; __hip_bfloat16 h[8]; } u;
#pragma unroll
        for (int j = 0; j < 8; ++j) {
            float w = ma[j] ? 0.0f : ((float)qa[j] * c - 1.0f) * s;
            u.h[j] = __float2bfloat16(w);
        }
        *(int4*)(Wb + base) = u.v;
    }
}

// ---------------------------------------------------------------------------
// async global->LDS, 16 B/lane, wave-uniform LDS base (HW adds lane*16)
// ---------------------------------------------------------------------------
__device__ __forceinline__ void gl_lds16(const __hip_bfloat16* g, __hip_bfloat16* l)
{
    __builtin_amdgcn_global_load_lds(
        (const __attribute__((address_space(1))) void*)g,
        (__attribute__((address_space(3))) void*)l,
        16, 0, 0);
}

// ---------------------------------------------------------------------------
// 256x256x64 8-phase bf16 MFMA GEMM (T2+T3+T4+T5+T1), 512 threads = 8 waves
// (wm = wave>>2 in {0,1}, wn = wave&3 in {0..3}); per-wave output 128(M)x64(N)
// via WAVE-INTERLEAVED frags: x row = i*32+wm*16+lr (i=0..7),
// W row = j*64+wn*16+lr (j=0..3).  Role-swapped MFMA (A-op = W) as before:
// C/D n = lr -> s, m = quad*4+reg -> o  => float4 C stores.
//
// Region-freeing schedule (2 LDS buffers, 128 KiB, NO vmcnt(0) in main loop):
//   reads:  P1 = A(i0-3)+B(j0-1)  [frees A-h0, B-h0 of buf]
//           P2 = B(j2-3)          [frees B-h1]
//           P3 = A(i4-7)          [frees A-h1]     P4 = none
//   stages: P1 -> B-h0(t+1) into buf^1      (other buffer, always safe)
//           P2 -> A-h0(t+2) into buf        (A-h0 freed at P1 end-barrier)
//           P3 -> B-h1(t+2)                 (freed at P2)
//           P4 -> A-h1(t+2)                 (freed at P3)
//   P4: s_waitcnt vmcnt(6) = 3 half-tiles (last 3 stages) in flight; the
//   4th-oldest (B-h0(t+1) from P1) and older are complete => tile t+1 fully
//   resident before its P1 reads.  Same XOR swizzle as the verified 128²
//   kernel: logical col-block cb of row r lives at physical cb^(r&7).
// ---------------------------------------------------------------------------
#define LDA(S, I, K) bA[S][K] = *(const bf16x8*)(Asb + ((I) * 32 + wm16 + lr) * 64 + ((((quad) + (K) * 4) ^ swr) * 8))
#define LDB(J, K)    bB[J][K] = *(const bf16x8*)(Bsb + ((J) * 64 + wn16 + lr) * 64 + ((((quad) + (K) * 4) ^ swr) * 8))

#define MMQ(IB, JB) do { \
    _Pragma("unroll") \
    for (int _jj = 0; _jj < 2; ++_jj) \
        _Pragma("unroll") \
        for (int _ii = 0; _ii < 4; ++_ii) \
            _Pragma("unroll") \
            for (int _kk = 0; _kk < 2; ++_kk) \
                acc[(IB) + _ii][(JB) + _jj] = __builtin_amdgcn_mfma_f32_16x16x32_bf16( \
                    bB[(JB) + _jj][_kk], bA[_ii][_kk], acc[(IB) + _ii][(JB) + _jj], 0, 0, 0); \
} while (0)

// stage one 16 KB half-tile: chunks c = wave*2+t cover rows HF*128+c*8..+7;
// lane supplies row +lane/8, pre-swizzled global col-block ((lane&7)^(lane>>3))
#define STAGE(gbase, ldsbase, k0, HF) do { \
    _Pragma("unroll") \
    for (int _t = 0; _t < 2; ++_t) { \
        const int _c = wave * 2 + _t; \
        const int _r = (HF) * 128 + _c * 8 + lrow; \
        gl_lds16((gbase) + (size_t)_r * IN_F + (k0) + lcol, (ldsbase) + _c * 512); \
    } \
} while (0)

#define TILE(BUF, T, SP1, SP2, VMODE) do { \
    const __hip_bfloat16* Asb = &As[(BUF)][0]; \
    const __hip_bfloat16* Bsb = &Bs[(BUF)][0]; \
    /* ---- P1 ---- */ \
    LDA(0,0,0); LDA(0,0,1); LDA(1,1,0); LDA(1,1,1); \
    LDA(2,2,0); LDA(2,2,1); LDA(3,3,0); LDA(3,3,1); \
    LDB(0,0);   LDB(0,1);   LDB(1,0);   LDB(1,1); \
    if (SP1) STAGE(Bblk, &Bs[(BUF)^1][0], ((T)+1)*BK, 0); \
    __builtin_amdgcn_s_barrier(); \
    asm volatile("s_waitcnt lgkmcnt(0)" ::: "memory"); \
    __builtin_amdgcn_s_setprio(1); MMQ(0,0); __builtin_amdgcn_s_setprio(0); \
    __builtin_amdgcn_s_barrier(); \
    /* ---- P2 ---- */ \
    LDB(2,0); LDB(2,1); LDB(3,0); LDB(3,1); \
    if (SP2) STAGE(Ablk, &As[(BUF)][0], ((T)+2)*BK, 0); \
    __builtin_amdgcn_s_barrier(); \
    asm volatile("s_waitcnt lgkmcnt(0)" ::: "memory"); \
    __builtin_amdgcn_s_setprio(1); MMQ(0,2); __builtin_amdgcn_s_setprio(0); \
    __builtin_amdgcn_s_barrier(); \
    /* ---- P3 ---- */ \
    LDA(0,4,0); LDA(0,4,1); LDA(1,5,0); LDA(1,5,1); \
    LDA(2,6,0); LDA(2,6,1); LDA(3,7,0); LDA(3,7,1); \
    if (SP2) STAGE(Bblk, &Bs[(BUF)][128*64], ((T)+2)*BK, 1); \
    __builtin_amdgcn_s_barrier(); \
    asm volatile("s_waitcnt lgkmcnt(0)" ::: "memory"); \
    __builtin_amdgcn_s_setprio(1); MMQ(4,0); __builtin_amdgcn_s_setprio(0); \
    __builtin_amdgcn_s_barrier(); \
    /* ---- P4 ---- */ \
    if (SP2) STAGE(Ablk, &As[(BUF)][128*64], ((T)+2)*BK, 1); \
    __builtin_amdgcn_s_barrier(); \
    if ((VMODE) == 2)      asm volatile("s_waitcnt vmcnt(6)" ::: "memory"); \
    else if ((VMODE) == 1) asm volatile("s_waitcnt vmcnt(0)" ::: "memory"); \
    __builtin_amdgcn_s_setprio(1); MMQ(4,2); __builtin_amdgcn_s_setprio(0); \
    __builtin_amdgcn_s_barrier(); \
} while (0)

__global__ __launch_bounds__(512, 2) void k_gemm(const __hip_bfloat16* __restrict__ A,
                                                 const __hip_bfloat16* __restrict__ B,
                                                 const float* __restrict__ bias,
                                                 float* __restrict__ C)
{
    __shared__ __align__(16) __hip_bfloat16 As[2][BM * BK];   // 2 x 32 KB (x)
    __shared__ __align__(16) __hip_bfloat16 Bs[2][BN * BK];   // 2 x 32 KB (W)

    const int tid  = threadIdx.x;
    const int lane = tid & 63;
    const int wave = tid >> 6;          // 0..7
    const int wm16 = (wave >> 2) * 16;  // 0,16  (M interleave)
    const int wn16 = (wave & 3) * 16;   // 0..48 (N interleave)
    const int quad = lane >> 4;         // 0..3
    const int lr   = lane & 15;
    const int swr  = lr & 7;            // read-side swizzle key (= row&7)
    const int lrow = lane >> 3;         // staging: row within 8-row chunk
    const int lcol = ((lane & 7) ^ lrow) * 8;   // pre-swizzled global col

    // T1: bijective XCD swizzle (688 % 8 == 0); M fastest within each chunk
    const int orig = blockIdx.x;
    const int swz  = (orig & 7) * (688 >> 3) + (orig >> 3);
    const int bm   = swz & 15;          // 0..15
    const int bn   = swz >> 4;          // 0..42

    const __hip_bfloat16* Ablk = A + (size_t)bm * BM * IN_F;
    const __hip_bfloat16* Bblk = B + (size_t)bn * BN * IN_F;

    bf16x8 bA[4][2];    // current 4 M-frags (i0-3 then i4-7), 2 k-slices
    bf16x8 bB[4][2];    // all 4 N-frags, live across the tile
    f32x4  acc[8][4];
#pragma unroll
    for (int i = 0; i < 8; ++i)
#pragma unroll
        for (int j = 0; j < 4; ++j)
            acc[i][j] = (f32x4){0.f, 0.f, 0.f, 0.f};

    // prologue: tile0 all 4 halves + tile1's {A-h0, B-h1, A-h1}
    // (tile1's B-h0 is staged at t=0 P1, matching steady state)
    STAGE(Bblk, &Bs[0][0],      0,  0);
    STAGE(Ablk, &As[0][0],      0,  0);
    STAGE(Bblk, &Bs[0][128*64], 0,  1);
    STAGE(Ablk, &As[0][128*64], 0,  1);
    STAGE(Ablk, &As[1][0],      BK, 0);
    STAGE(Bblk, &Bs[1][128*64], BK, 1);
    STAGE(Ablk, &As[1][128*64], BK, 1);
    asm volatile("s_waitcnt vmcnt(6)" ::: "memory");   // tile0 resident, 3 halves in flight
    __builtin_amdgcn_s_barrier();

    // main loop: tiles 0..NT-3 (62 tiles = 31 buffer pairs), steady schedule
    for (int u = 0; u < (NT - 2) / 2; ++u) {
        const int t0 = 2 * u;
        TILE(0, t0,     1, 1, 2);
        TILE(1, t0 + 1, 1, 1, 2);
    }
    // tail: tile NT-2 (stages only B-h0(NT-1); drain), tile NT-1 (no stages)
    TILE(0, NT - 2, 1, 0, 1);
    TILE(1, NT - 1, 0, 0, 0);

    // epilogue: lane holds 4 consecutive o per frag -> float4 store + bias
#pragma unroll
    for (int j = 0; j < 4; ++j) {
        const int o = bn * BN + j * 64 + wn16 + quad * 4;
        const float4 bv = *(const float4*)(bias + o);
#pragma unroll
        for (int i = 0; i < 8; ++i) {
            const int s = bm * BM + i * 32 + wm16 + lr;
            float4 v;
            v.x = acc[i][j][0] + bv.x;
            v.y = acc[i][j][1] + bv.y;
            v.z = acc[i][j][2] + bv.z;
            v.w = acc[i][j][3] + bv.w;
            *(float4*)(C + (size_t)s * OUT_F + o) = v;
        }
    }
}

extern "C" void kernel_launch(void* const* d_in, const int* in_sizes, int n_in,
                              void* d_out, int out_size, void* d_ws, size_t ws_size,
                              hipStream_t stream)
{
    const float* x      = (const float*)d_in[0];
    const int*   q      = (const int*)d_in[1];
    const float* scales = (const float*)d_in[2];
    const int*   mask   = (const int*)d_in[3];
    const float* bias   = (const float*)d_in[4];
    float* out          = (float*)d_out;

    __hip_bfloat16* xb = (__hip_bfloat16*)d_ws;                 // 33.5 MB
    __hip_bfloat16* Wb = xb + (size_t)MROWS * IN_F;             // 90.2 MB

    k_prep<<<CVT_BLOCKS + DEQ_BLOCKS, 256, 0, stream>>>(x, q, mask, scales, xb, Wb);

    k_gemm<<<dim3(688), dim3(512), 0, stream>>>(xb, Wb, bias, out);
}

// Round 2
// 834.163 us; speedup vs baseline: 1.1851x; 1.0530x over previous
//
#include <hip/hip_runtime.h>
#include <hip/hip_bf16.h>

#define IN_F   4096
#define OUT_F  11008
#define MROWS  4096   // 2*2048 rows of x
#define BM     256
#define BN     256
#define BK     64
#define NT     (IN_F / BK)                           // 64 K-tiles
#define CVT_CHUNKS (((long long)MROWS * IN_F) / 8)   // 2,097,152
#define TOT_CHUNKS (((long long)(MROWS + OUT_F) * IN_F) / 8)  // 7,733,248
#define PREP_GRID  2048

typedef __bf16 bf16x8 __attribute__((ext_vector_type(8)));
typedef float  f32x4  __attribute__((ext_vector_type(4)));

// ---------------------------------------------------------------------------
// Prep, now GRID-STRIDE at 2048 blocks (G11): diagnostic for the ~400 µs gap.
// Math identical to R1. CVT range = 4 full strides (2,097,152 = 4*524,288),
// so every iteration's branch is block-uniform.
// ---------------------------------------------------------------------------
__global__ __launch_bounds__(256) void k_prep(const float* __restrict__ x,
                                              const int* __restrict__ q,
                                              const int* __restrict__ mask,
                                              const float* __restrict__ scales,
                                              __hip_bfloat16* __restrict__ xb,
                                              __hip_bfloat16* __restrict__ Wb)
{
    const long long stride = (long long)PREP_GRID * 256;
    for (long long c = (long long)blockIdx.x * 256 + threadIdx.x; c < TOT_CHUNKS; c += stride) {
        if (c < CVT_CHUNKS) {
            const long long base = c * 8;
            const float4 a = *(const float4*)(x + base);
            const float4 b = *(const float4*)(x + base + 4);
            float f[8] = {a.x, a.y, a.z, a.w, b.x, b.y, b.z, b.w};
            union { int4 v; __hip_bfloat16 h[8]; } u;
#pragma unroll
            for (int j = 0; j < 8; ++j) u.h[j] = __float2bfloat16(f[j]);
            *(int4*)(xb + base) = u.v;
        } else {
            const long long base = (c - CVT_CHUNKS) * 8;
            const int   g = (int)(base >> 6);
            const float s = scales[g];
            const int4 q0 = *(const int4*)(q + base);
            const int4 q1 = *(const int4*)(q + base + 4);
            const int4 m0 = *(const int4*)(mask + base);
            const int4 m1 = *(const int4*)(mask + base + 4);
            const float cc = 2.0f / 7.0f;
            int qa[8] = {q0.x, q0.y, q0.z, q0.w, q1.x, q1.y, q1.z, q1.w};
            int ma[8] = {m0.x, m0.y, m0.z, m0.w, m1.x, m1.y, m1.z, m1.w};
            union { int4 v; __hip_bfloat16 h[8]; } u;
#pragma unroll
            for (int j = 0; j < 8; ++j) {
                float w = ma[j] ? 0.0f : ((float)qa[j] * cc - 1.0f) * s;
                u.h[j] = __float2bfloat16(w);
            }
            *(int4*)(Wb + base) = u.v;
        }
    }
}

// ---------------------------------------------------------------------------
// async global->LDS, 16 B/lane, wave-uniform LDS base (HW adds lane*16)
// ---------------------------------------------------------------------------
__device__ __forceinline__ void gl_lds16(const __hip_bfloat16* g, __hip_bfloat16* l)
{
    __builtin_amdgcn_global_load_lds(
        (const __attribute__((address_space(1))) void*)g,
        (__attribute__((address_space(3))) void*)l,
        16, 0, 0);
}

// ---------------------------------------------------------------------------
// 256x256x64 8-phase bf16 GEMM, R2: exact m201 read distribution 8/4/8/4.
//   P1: read bA(i0-3)        | stage B-h0(t+1)->buf^1 | bar | lgkm0 | MMQ(0,0)
//   P2: read bB(j2-3)        | stage A-h0(t+2)        | bar | lgkm0 | MMQ(0,2)
//   P3: read bA(i4-7)        | stage B-h1(t+2)        | bar | lgkm0 | MMQ(4,0)
//   P4:                        stage A-h1(t+2)        | bar | vmcnt(6)
//       read bB'(j0-1) of t+1 from buf^1 (region retired by the vmcnt)
//       | sched_barrier | MMQ(4,2)  [no lgkm wait: operands drained P2/P3;
//         the bB' reads drain at P1(t+1)'s lgkm0]
// All ds_reads are base-reg + 16-bit immediate offset (6 base regs, zero
// per-read VALU; max imm 28672 B). vmcnt(6) bookkeeping: at P4(t) the 6
// newest = t+2's three half-tiles; retiring the 4th-oldest pair (B-h0(t+1),
// issued P1(t)) makes tile t+1 fully resident AND its h0 readable for bB'.
// Cross-wave DMA/read races are separated by >=1 MFMA phase + barrier
// (same margin class as the verified m201 template).
// ---------------------------------------------------------------------------
#define MMQ(IB, JB) do { \
    _Pragma("unroll") \
    for (int _jj = 0; _jj < 2; ++_jj) \
        _Pragma("unroll") \
        for (int _ii = 0; _ii < 4; ++_ii) \
            _Pragma("unroll") \
            for (int _kk = 0; _kk < 2; ++_kk) \
                acc[(IB) + _ii][(JB) + _jj] = __builtin_amdgcn_mfma_f32_16x16x32_bf16( \
                    bB[(JB) + _jj][_kk], bA[_ii][_kk], acc[(IB) + _ii][(JB) + _jj], 0, 0, 0); \
} while (0)

// stage one 16 KB half-tile: chunks c = wave*2+t cover rows HF*128+c*8..+7;
// lane supplies row +lane/8, pre-swizzled global col-block ((lane&7)^(lane>>3))
#define STAGE(gbase, ldsbase, k0, HF) do { \
    _Pragma("unroll") \
    for (int _t = 0; _t < 2; ++_t) { \
        const int _c = wave * 2 + _t; \
        const int _r = (HF) * 128 + _c * 8 + lrow; \
        gl_lds16((gbase) + (size_t)_r * IN_F + (k0) + lcol, (ldsbase) + _c * 512); \
    } \
} while (0)

#define TILE(BUF, T, SP1, SP2, VMODE, RD4) do { \
    const __hip_bfloat16* pA  = &As[(BUF)][0] + offA;        /* bases: +x0/+x1 per k */ \
    const __hip_bfloat16* pB  = &Bs[(BUF)][0] + offB; \
    const __hip_bfloat16* pBn = &Bs[(BUF)^1][0] + offB; \
    /* ---- P1: 8 x ds_read bA(i0-3) ---- */ \
    bA[0][0] = *(const bf16x8*)(pA + x0);        bA[0][1] = *(const bf16x8*)(pA + x1); \
    bA[1][0] = *(const bf16x8*)(pA + x0 + 2048); bA[1][1] = *(const bf16x8*)(pA + x1 + 2048); \
    bA[2][0] = *(const bf16x8*)(pA + x0 + 4096); bA[2][1] = *(const bf16x8*)(pA + x1 + 4096); \
    bA[3][0] = *(const bf16x8*)(pA + x0 + 6144); bA[3][1] = *(const bf16x8*)(pA + x1 + 6144); \
    if (SP1) STAGE(Bblk, &Bs[(BUF)^1][0], ((T)+1)*BK, 0); \
    __builtin_amdgcn_s_barrier(); \
    asm volatile("s_waitcnt lgkmcnt(0)" ::: "memory"); \
    __builtin_amdgcn_s_setprio(1); MMQ(0,0); __builtin_amdgcn_s_setprio(0); \
    __builtin_amdgcn_s_barrier(); \
    /* ---- P2: 4 x ds_read bB(j2-3) ---- */ \
    bB[2][0] = *(const bf16x8*)(pB + x0 + 8192);  bB[2][1] = *(const bf16x8*)(pB + x1 + 8192); \
    bB[3][0] = *(const bf16x8*)(pB + x0 + 12288); bB[3][1] = *(const bf16x8*)(pB + x1 + 12288); \
    if (SP2) STAGE(Ablk, &As[(BUF)][0], ((T)+2)*BK, 0); \
    __builtin_amdgcn_s_barrier(); \
    asm volatile("s_waitcnt lgkmcnt(0)" ::: "memory"); \
    __builtin_amdgcn_s_setprio(1); MMQ(0,2); __builtin_amdgcn_s_setprio(0); \
    __builtin_amdgcn_s_barrier(); \
    /* ---- P3: 8 x ds_read bA(i4-7) ---- */ \
    bA[0][0] = *(const bf16x8*)(pA + x0 + 8192);  bA[0][1] = *(const bf16x8*)(pA + x1 + 8192); \
    bA[1][0] = *(const bf16x8*)(pA + x0 + 10240); bA[1][1] = *(const bf16x8*)(pA + x1 + 10240); \
    bA[2][0] = *(const bf16x8*)(pA + x0 + 12288); bA[2][1] = *(const bf16x8*)(pA + x1 + 12288); \
    bA[3][0] = *(const bf16x8*)(pA + x0 + 14336); bA[3][1] = *(const bf16x8*)(pA + x1 + 14336); \
    if (SP2) STAGE(Bblk, &Bs[(BUF)][128*64], ((T)+2)*BK, 1); \
    __builtin_amdgcn_s_barrier(); \
    asm volatile("s_waitcnt lgkmcnt(0)" ::: "memory"); \
    __builtin_amdgcn_s_setprio(1); MMQ(4,0); __builtin_amdgcn_s_setprio(0); \
    __builtin_amdgcn_s_barrier(); \
    /* ---- P4: stage, counted vmcnt, early-read next tile's bB(j0-1) ---- */ \
    if (SP2) STAGE(Ablk, &As[(BUF)][128*64], ((T)+2)*BK, 1); \
    __builtin_amdgcn_s_barrier(); \
    if ((VMODE) == 2)      asm volatile("s_waitcnt vmcnt(6)" ::: "memory"); \
    else if ((VMODE) == 1) asm volatile("s_waitcnt vmcnt(0)" ::: "memory"); \
    if (RD4) { \
        bB[0][0] = *(const bf16x8*)(pBn + x0);        bB[0][1] = *(const bf16x8*)(pBn + x1); \
        bB[1][0] = *(const bf16x8*)(pBn + x0 + 4096); bB[1][1] = *(const bf16x8*)(pBn + x1 + 4096); \
        __builtin_amdgcn_sched_barrier(0);  /* pin reads before the MFMA cluster */ \
    } \
    __builtin_amdgcn_s_setprio(1); MMQ(4,2); __builtin_amdgcn_s_setprio(0); \
    __builtin_amdgcn_s_barrier(); \
} while (0)

__global__ __launch_bounds__(512, 2) void k_gemm(const __hip_bfloat16* __restrict__ A,
                                                 const __hip_bfloat16* __restrict__ B,
                                                 const float* __restrict__ bias,
                                                 float* __restrict__ C)
{
    __shared__ __align__(16) __hip_bfloat16 As[2][BM * BK];   // 2 x 32 KB (x)
    __shared__ __align__(16) __hip_bfloat16 Bs[2][BN * BK];   // 2 x 32 KB (W)

    const int tid  = threadIdx.x;
    const int lane = tid & 63;
    const int wave = tid >> 6;          // 0..7
    const int wm16 = (wave >> 2) * 16;  // 0,16  (M interleave)
    const int wn16 = (wave & 3) * 16;   // 0..48 (N interleave)
    const int quad = lane >> 4;         // 0..3
    const int lr   = lane & 15;
    const int swr  = lr & 7;            // read-side swizzle key (= row&7)
    const int lrow = lane >> 3;         // staging: row within 8-row chunk
    const int lcol = ((lane & 7) ^ lrow) * 8;   // pre-swizzled global col

    // ds_read base offsets (elements): row term + XOR'd col-block for k=0/1.
    // ((quad+4)^swr)*8 == ((quad^swr)*8) ^ 32, so x1 = x0 ^ 32.
    const int offA = (wm16 + lr) * 64;
    const int offB = (wn16 + lr) * 64;
    const int x0   = (quad ^ swr) * 8;
    const int x1   = x0 ^ 32;

    // T1: bijective XCD swizzle (688 % 8 == 0); M fastest within each chunk
    const int orig = blockIdx.x;
    const int swz  = (orig & 7) * (688 >> 3) + (orig >> 3);
    const int bm   = swz & 15;          // 0..15
    const int bn   = swz >> 4;          // 0..42

    const __hip_bfloat16* Ablk = A + (size_t)bm * BM * IN_F;
    const __hip_bfloat16* Bblk = B + (size_t)bn * BN * IN_F;

    bf16x8 bA[4][2];    // current 4 M-frags (i0-3 or i4-7), 2 k-slices
    bf16x8 bB[4][2];    // all 4 N-frags; j0-1 loaded one phase early (P4)
    f32x4  acc[8][4];
#pragma unroll
    for (int i = 0; i < 8; ++i)
#pragma unroll
        for (int j = 0; j < 4; ++j)
            acc[i][j] = (f32x4){0.f, 0.f, 0.f, 0.f};

    // prologue: tile0 all 4 halves + tile1's {A-h0, B-h1, A-h1}
    // (tile1's B-h0 is staged at t=0 P1, matching steady state)
    STAGE(Bblk, &Bs[0][0],      0,  0);
    STAGE(Ablk, &As[0][0],      0,  0);
    STAGE(Bblk, &Bs[0][128*64], 0,  1);
    STAGE(Ablk, &As[0][128*64], 0,  1);
    STAGE(Ablk, &As[1][0],      BK, 0);
    STAGE(Bblk, &Bs[1][128*64], BK, 1);
    STAGE(Ablk, &As[1][128*64], BK, 1);
    asm volatile("s_waitcnt vmcnt(6)" ::: "memory");   // tile0 resident, 3 halves in flight
    __builtin_amdgcn_s_barrier();
    {   // pre-read tile0's bB(j0-1) (steady state reads these at P4(t-1))
        const __hip_bfloat16* pB0 = &Bs[0][0] + offB;
        bB[0][0] = *(const bf16x8*)(pB0 + x0);        bB[0][1] = *(const bf16x8*)(pB0 + x1);
        bB[1][0] = *(const bf16x8*)(pB0 + x0 + 4096); bB[1][1] = *(const bf16x8*)(pB0 + x1 + 4096);
    }

    // main loop: tiles 0..61 steady, then 62 (drain) and 63 (no stages)
    for (int u = 0; u < (NT - 2) / 2; ++u) {
        const int t0 = 2 * u;
        TILE(0, t0,     1, 1, 2, 1);
        TILE(1, t0 + 1, 1, 1, 2, 1);
    }
    TILE(0, NT - 2, 1, 0, 1, 1);
    TILE(1, NT - 1, 0, 0, 0, 0);

    // epilogue: lane holds 4 consecutive o per frag -> float4 store + bias
#pragma unroll
    for (int j = 0; j < 4; ++j) {
        const int o = bn * BN + j * 64 + wn16 + quad * 4;
        const float4 bv = *(const float4*)(bias + o);
#pragma unroll
        for (int i = 0; i < 8; ++i) {
            const int s = bm * BM + i * 32 + wm16 + lr;
            float4 v;
            v.x = acc[i][j][0] + bv.x;
            v.y = acc[i][j][1] + bv.y;
            v.z = acc[i][j][2] + bv.z;
            v.w = acc[i][j][3] + bv.w;
            *(float4*)(C + (size_t)s * OUT_F + o) = v;
        }
    }
}

extern "C" void kernel_launch(void* const* d_in, const int* in_sizes, int n_in,
                              void* d_out, int out_size, void* d_ws, size_t ws_size,
                              hipStream_t stream)
{
    const float* x      = (const float*)d_in[0];
    const int*   q      = (const int*)d_in[1];
    const float* scales = (const float*)d_in[2];
    const int*   mask   = (const int*)d_in[3];
    const float* bias   = (const float*)d_in[4];
    float* out          = (float*)d_out;

    __hip_bfloat16* xb = (__hip_bfloat16*)d_ws;                 // 33.5 MB
    __hip_bfloat16* Wb = xb + (size_t)MROWS * IN_F;             // 90.2 MB

    k_prep<<<PREP_GRID, 256, 0, stream>>>(x, q, mask, scales, xb, Wb);

    k_gemm<<<dim3(688), dim3(512), 0, stream>>>(xb, Wb, bias, out);
}

// Round 6
// 784.226 us; speedup vs baseline: 1.2606x; 1.0637x over previous
//
#include <hip/hip_runtime.h>
#include <hip/hip_bf16.h>

// R6 = R3/R5 schedule + race fixes:
//  (a) prologue pre-read now drained (lgkm0) + barrier BEFORE the loop --
//      P1(0)'s B-h0(2) DMA could previously land before slow waves finished
//      the pre-read of tile 0's B-h0 (same region, same barrier epoch).
//  (b) s_barrier between P4's vmcnt(8) and the early-read: cross-wave
//      DMA-completion guarantee (writer-vmcnt -> barrier -> read).

#define IN_F   4096
#define OUT_F  11008
#define MROWS  4096   // 2*2048 rows of x
#define BM     256
#define BN     256
#define BK     64
#define NT     (IN_F / BK)                           // 64 K-tiles

#define X_ELEMS ((long long)MROWS * IN_F)            // 16,777,216
#define W_ELEMS ((long long)OUT_F * IN_F)            // 45,088,768
#define XPREP_BLOCKS ((int)(X_ELEMS / (256 * 4)))    // 16384
#define WPREP_BLOCKS ((int)(W_ELEMS / (256 * 4)))    // 44032

typedef __bf16 bf16x8 __attribute__((ext_vector_type(8)));
typedef float  f32x4  __attribute__((ext_vector_type(4)));
typedef int    i32x4  __attribute__((ext_vector_type(4)));
typedef unsigned int u32x2 __attribute__((ext_vector_type(2)));

// ---------------------------------------------------------------------------
// Prep: 4 elems/thread -> every load is DENSE 16 B/lane. Non-temporal loads
// on q/mask/x (read once) keep xb/Wb L3-resident for the gemm.
// ---------------------------------------------------------------------------
__global__ __launch_bounds__(256) void k_prep(const float* __restrict__ x,
                                              const int* __restrict__ q,
                                              const int* __restrict__ mask,
                                              const float* __restrict__ scales,
                                              __hip_bfloat16* __restrict__ xb,
                                              __hip_bfloat16* __restrict__ Wb)
{
    if (blockIdx.x < XPREP_BLOCKS) {
        const long long t    = (long long)blockIdx.x * 256 + threadIdx.x;
        const long long base = t * 4;
        const f32x4 a = __builtin_nontemporal_load((const f32x4*)(x + base));
        union { u32x2 v; __hip_bfloat16 h[4]; } u;
#pragma unroll
        for (int j = 0; j < 4; ++j) u.h[j] = __float2bfloat16(a[j]);
        *(u32x2*)(xb + base) = u.v;
    } else {
        const long long t    = (long long)(blockIdx.x - XPREP_BLOCKS) * 256 + threadIdx.x;
        const long long base = t * 4;
        const float s  = scales[base >> 6];
        const i32x4 qv = __builtin_nontemporal_load((const i32x4*)(q + base));
        const i32x4 mv = __builtin_nontemporal_load((const i32x4*)(mask + base));
        const float c = 2.0f / 7.0f;
        union { u32x2 v; __hip_bfloat16 h[4]; } u;
#pragma unroll
        for (int j = 0; j < 4; ++j) {
            float w = mv[j] ? 0.0f : ((float)qv[j] * c - 1.0f) * s;
            u.h[j] = __float2bfloat16(w);
        }
        *(u32x2*)(Wb + base) = u.v;
    }
}

// ---------------------------------------------------------------------------
// async global->LDS, 16 B/lane, wave-uniform LDS base (HW adds lane*16)
// ---------------------------------------------------------------------------
__device__ __forceinline__ void gl_lds16(const __hip_bfloat16* g, __hip_bfloat16* l)
{
    __builtin_amdgcn_global_load_lds(
        (const __attribute__((address_space(1))) void*)g,
        (__attribute__((address_space(3))) void*)l,
        16, 0, 0);
}

// ---------------------------------------------------------------------------
// 256x256x64 8-phase bf16 GEMM: ALL stages at depth t+2 into the CURRENT
// buffer, one half-tile per phase, each issued right after its region's last
// reader's drain+barrier:
//   P1: read bA(i0-3)  | stage B-h0(t+2)->buf | bar | lgkm0 | MMQ(0,0) | bar
//   P2: read bB(j2-3)  | stage A-h0(t+2)->buf | bar | lgkm0 | MMQ(0,2) | bar
//   P3: read bA(i4-7)  | stage B-h1(t+2)->buf | bar | lgkm0 | MMQ(4,0) | bar
//   P4: stage A-h1(t+2)->buf | bar | vmcnt(8) | bar   <- (b) cross-wave safe
//       read bB'(j0-1) of t+1 from buf^1 | sched_barrier | MMQ(4,2)
//       | lgkm0 (drains early-read before next P1's B-h0 DMA) | bar
// vmcnt(8): entering tile t, in-flight = t+1's 8 (staged during t-1); during
// t we issue t+2's 8; vmcnt(8) at P4(t) retires ALL of t+1 -> resident for
// the early-read (after the barrier) and P1(t+1).
// ---------------------------------------------------------------------------
#define MMQ(IB, JB) do { \
    _Pragma("unroll") \
    for (int _jj = 0; _jj < 2; ++_jj) \
        _Pragma("unroll") \
        for (int _ii = 0; _ii < 4; ++_ii) \
            _Pragma("unroll") \
            for (int _kk = 0; _kk < 2; ++_kk) \
                acc[(IB) + _ii][(JB) + _jj] = __builtin_amdgcn_mfma_f32_16x16x32_bf16( \
                    bB[(JB) + _jj][_kk], bA[_ii][_kk], acc[(IB) + _ii][(JB) + _jj], 0, 0, 0); \
} while (0)

// stage one 16 KB half-tile: chunks c = wave*2+t cover rows HF*128+c*8..+7;
// lane supplies row +lane/8, pre-swizzled global col-block ((lane&7)^(lane>>3))
#define STAGE(gbase, ldsbase, k0, HF) do { \
    _Pragma("unroll") \
    for (int _t = 0; _t < 2; ++_t) { \
        const int _c = wave * 2 + _t; \
        const int _r = (HF) * 128 + _c * 8 + lrow; \
        gl_lds16((gbase) + (size_t)_r * IN_F + (k0) + lcol, (ldsbase) + _c * 512); \
    } \
} while (0)

#define TILE(BUF, T, SP, VMODE, RD4) do { \
    const __hip_bfloat16* pA  = &As[(BUF)][0] + offA; \
    const __hip_bfloat16* pB  = &Bs[(BUF)][0] + offB; \
    const __hip_bfloat16* pBn = &Bs[(BUF)^1][0] + offB; \
    /* ---- P1: 8 x ds_read bA(i0-3); stage B-h0(t+2) ---- */ \
    bA[0][0] = *(const bf16x8*)(pA + x0);        bA[0][1] = *(const bf16x8*)(pA + x1); \
    bA[1][0] = *(const bf16x8*)(pA + x0 + 2048); bA[1][1] = *(const bf16x8*)(pA + x1 + 2048); \
    bA[2][0] = *(const bf16x8*)(pA + x0 + 4096); bA[2][1] = *(const bf16x8*)(pA + x1 + 4096); \
    bA[3][0] = *(const bf16x8*)(pA + x0 + 6144); bA[3][1] = *(const bf16x8*)(pA + x1 + 6144); \
    if (SP) STAGE(Bblk, &Bs[(BUF)][0], ((T)+2)*BK, 0); \
    __builtin_amdgcn_s_barrier(); \
    asm volatile("s_waitcnt lgkmcnt(0)" ::: "memory"); \
    __builtin_amdgcn_s_setprio(1); MMQ(0,0); __builtin_amdgcn_s_setprio(0); \
    __builtin_amdgcn_s_barrier(); \
    /* ---- P2: 4 x ds_read bB(j2-3); stage A-h0(t+2) ---- */ \
    bB[2][0] = *(const bf16x8*)(pB + x0 + 8192);  bB[2][1] = *(const bf16x8*)(pB + x1 + 8192); \
    bB[3][0] = *(const bf16x8*)(pB + x0 + 12288); bB[3][1] = *(const bf16x8*)(pB + x1 + 12288); \
    if (SP) STAGE(Ablk, &As[(BUF)][0], ((T)+2)*BK, 0); \
    __builtin_amdgcn_s_barrier(); \
    asm volatile("s_waitcnt lgkmcnt(0)" ::: "memory"); \
    __builtin_amdgcn_s_setprio(1); MMQ(0,2); __builtin_amdgcn_s_setprio(0); \
    __builtin_amdgcn_s_barrier(); \
    /* ---- P3: 8 x ds_read bA(i4-7); stage B-h1(t+2) ---- */ \
    bA[0][0] = *(const bf16x8*)(pA + x0 + 8192);  bA[0][1] = *(const bf16x8*)(pA + x1 + 8192); \
    bA[1][0] = *(const bf16x8*)(pA + x0 + 10240); bA[1][1] = *(const bf16x8*)(pA + x1 + 10240); \
    bA[2][0] = *(const bf16x8*)(pA + x0 + 12288); bA[2][1] = *(const bf16x8*)(pA + x1 + 12288); \
    bA[3][0] = *(const bf16x8*)(pA + x0 + 14336); bA[3][1] = *(const bf16x8*)(pA + x1 + 14336); \
    if (SP) STAGE(Bblk, &Bs[(BUF)][128*64], ((T)+2)*BK, 1); \
    __builtin_amdgcn_s_barrier(); \
    asm volatile("s_waitcnt lgkmcnt(0)" ::: "memory"); \
    __builtin_amdgcn_s_setprio(1); MMQ(4,0); __builtin_amdgcn_s_setprio(0); \
    __builtin_amdgcn_s_barrier(); \
    /* ---- P4: stage A-h1(t+2); vmcnt; BARRIER; early-read t+1's bB(j0-1) ---- */ \
    if (SP) STAGE(Ablk, &As[(BUF)][128*64], ((T)+2)*BK, 1); \
    __builtin_amdgcn_s_barrier(); \
    if ((VMODE) == 2)      asm volatile("s_waitcnt vmcnt(8)" ::: "memory"); \
    else if ((VMODE) == 1) asm volatile("s_waitcnt vmcnt(0)" ::: "memory"); \
    __builtin_amdgcn_s_barrier();   /* (b): all waves' DMAs retired before any read */ \
    if (RD4) { \
        bB[0][0] = *(const bf16x8*)(pBn + x0);        bB[0][1] = *(const bf16x8*)(pBn + x1); \
        bB[1][0] = *(const bf16x8*)(pBn + x0 + 4096); bB[1][1] = *(const bf16x8*)(pBn + x1 + 4096); \
        __builtin_amdgcn_sched_barrier(0);  /* pin reads before the MFMA cluster */ \
    } \
    __builtin_amdgcn_s_setprio(1); MMQ(4,2); __builtin_amdgcn_s_setprio(0); \
    if (RD4) asm volatile("s_waitcnt lgkmcnt(0)" ::: "memory"); /* drain early-read */ \
    __builtin_amdgcn_s_barrier(); \
} while (0)

__global__ __launch_bounds__(512, 2) void k_gemm(const __hip_bfloat16* __restrict__ A,
                                                 const __hip_bfloat16* __restrict__ B,
                                                 const float* __restrict__ bias,
                                                 float* __restrict__ C)
{
    __shared__ __align__(16) __hip_bfloat16 As[2][BM * BK];   // 2 x 32 KB (x)
    __shared__ __align__(16) __hip_bfloat16 Bs[2][BN * BK];   // 2 x 32 KB (W)

    const int tid  = threadIdx.x;
    const int lane = tid & 63;
    const int wave = tid >> 6;          // 0..7
    const int wm16 = (wave >> 2) * 16;  // 0,16  (M interleave)
    const int wn16 = (wave & 3) * 16;   // 0..48 (N interleave)
    const int quad = lane >> 4;         // 0..3
    const int lr   = lane & 15;
    const int swr  = lr & 7;            // read-side swizzle key (= row&7)
    const int lrow = lane >> 3;         // staging: row within 8-row chunk
    const int lcol = ((lane & 7) ^ lrow) * 8;   // pre-swizzled global col

    // ds_read base offsets (elements): row term + XOR'd col-block for k=0/1.
    const int offA = (wm16 + lr) * 64;
    const int offB = (wn16 + lr) * 64;
    const int x0   = (quad ^ swr) * 8;
    const int x1   = x0 ^ 32;

    // T1: bijective XCD swizzle (688 % 8 == 0); M fastest within each chunk
    const int orig = blockIdx.x;
    const int swz  = (orig & 7) * (688 >> 3) + (orig >> 3);
    const int bm   = swz & 15;          // 0..15
    const int bn   = swz >> 4;          // 0..42

    const __hip_bfloat16* Ablk = A + (size_t)bm * BM * IN_F;
    const __hip_bfloat16* Bblk = B + (size_t)bn * BN * IN_F;

    bf16x8 bA[4][2];    // current 4 M-frags (i0-3 or i4-7), 2 k-slices
    bf16x8 bB[4][2];    // all 4 N-frags; j0-1 loaded one phase early (P4)
    f32x4  acc[8][4];
#pragma unroll
    for (int i = 0; i < 8; ++i)
#pragma unroll
        for (int j = 0; j < 4; ++j)
            acc[i][j] = (f32x4){0.f, 0.f, 0.f, 0.f};

    // prologue: tiles 0 AND 1 fully staged (t0 -> buf0, t1 -> buf1);
    // vmcnt(8) = t0 resident, t1's 8 in flight == steady-state entry.
    STAGE(Bblk, &Bs[0][0],      0,  0);
    STAGE(Ablk, &As[0][0],      0,  0);
    STAGE(Bblk, &Bs[0][128*64], 0,  1);
    STAGE(Ablk, &As[0][128*64], 0,  1);
    STAGE(Bblk, &Bs[1][0],      BK, 0);
    STAGE(Ablk, &As[1][0],      BK, 0);
    STAGE(Bblk, &Bs[1][128*64], BK, 1);
    STAGE(Ablk, &As[1][128*64], BK, 1);
    asm volatile("s_waitcnt vmcnt(8)" ::: "memory");
    __builtin_amdgcn_s_barrier();
    {   // pre-read tile0's bB(j0-1) (steady state reads these at P4(t-1))
        const __hip_bfloat16* pB0 = &Bs[0][0] + offB;
        bB[0][0] = *(const bf16x8*)(pB0 + x0);        bB[0][1] = *(const bf16x8*)(pB0 + x1);
        bB[1][0] = *(const bf16x8*)(pB0 + x0 + 4096); bB[1][1] = *(const bf16x8*)(pB0 + x1 + 4096);
    }
    // (a) RACE FIX: drain the pre-read and barrier BEFORE P1(0) issues the
    // B-h0(2) DMA into the same LDS region (was same-epoch in R3/R5).
    asm volatile("s_waitcnt lgkmcnt(0)" ::: "memory");
    __builtin_amdgcn_s_barrier();

    // main loop: tiles 0..61 stage t+2 (covers tiles 2..63 exactly once)
    for (int u = 0; u < (NT - 2) / 2; ++u) {
        const int t0 = 2 * u;
        TILE(0, t0,     1, 2, 1);
        TILE(1, t0 + 1, 1, 2, 1);
    }
    TILE(0, NT - 2, 0, 1, 1);   // drain: no stages, vmcnt(0) retires t63's 8
    TILE(1, NT - 1, 0, 0, 0);   // all resident

    // epilogue: lane holds 4 consecutive o per frag -> float4 store + bias
#pragma unroll
    for (int j = 0; j < 4; ++j) {
        const int o = bn * BN + j * 64 + wn16 + quad * 4;
        const f32x4 bv = *(const f32x4*)(bias + o);
#pragma unroll
        for (int i = 0; i < 8; ++i) {
            const int s = bm * BM + i * 32 + wm16 + lr;
            f32x4 v = acc[i][j] + bv;
            *(f32x4*)(C + (size_t)s * OUT_F + o) = v;
        }
    }
}

extern "C" void kernel_launch(void* const* d_in, const int* in_sizes, int n_in,
                              void* d_out, int out_size, void* d_ws, size_t ws_size,
                              hipStream_t stream)
{
    const float* x      = (const float*)d_in[0];
    const int*   q      = (const int*)d_in[1];
    const float* scales = (const float*)d_in[2];
    const int*   mask   = (const int*)d_in[3];
    const float* bias   = (const float*)d_in[4];
    float* out          = (float*)d_out;

    __hip_bfloat16* xb = (__hip_bfloat16*)d_ws;                 // 33.5 MB
    __hip_bfloat16* Wb = xb + (size_t)MROWS * IN_F;             // 90.2 MB

    k_prep<<<XPREP_BLOCKS + WPREP_BLOCKS, 256, 0, stream>>>(x, q, mask, scales, xb, Wb);

    k_gemm<<<dim3(688), dim3(512), 0, stream>>>(xb, Wb, bias, out);
}